// Round 7
// baseline (1227.003 us; speedup 1.0000x reference)
//
#include <hip/hip_runtime.h>
#include <hip/hip_bf16.h>
#include <math.h>

#define NNODES 100000
#define NEDGES 1600000
#define EN     1700000                      // edges + self loops
#define ALLOCE (EN + 7 * NNODES + 64)       // CSR rows padded to multiple of 8
#define F_IN   256
#define F_MID  128
#define HID    128
#define NG     128
#define NOUT   64
#define SCAN_CHUNK 2048
#define NCHUNK ((NNODES + SCAN_CHUNK - 1) / SCAN_CHUNK)   // 49

typedef unsigned int  u32;
typedef unsigned short u16;

__device__ __forceinline__ float bfl(u32 u) { return __uint_as_float(u << 16); }
__device__ __forceinline__ float bfh(u32 u) { return __uint_as_float(u & 0xFFFF0000u); }
__device__ __forceinline__ u32 f2bf(float f) {           // round-to-nearest-even
    u32 x = __float_as_uint(f);
    return (x + 0x7FFFu + ((x >> 16) & 1u)) >> 16;
}

// ---------------------------------------------------------------- init
__global__ __launch_bounds__(256) void k_init(int* deg, float* gs, float* pooled) {
    int i = blockIdx.x * 256 + threadIdx.x;
    if (i < NNODES) deg[i] = 1;                 // self loop
    if (i < NG) gs[i] = 0.f;
    if (i < NG * HID) pooled[i] = 0.f;
}

// init padded edge arrays: src=0 (safe gather), dst=-1 (padding marker)
__global__ __launch_bounds__(256) void k_meta_init(int* srcs, int* dsts) {
    int i = blockIdx.x * 256 + threadIdx.x;
    if (i >= ALLOCE) return;
    srcs[i] = 0;
    dsts[i] = -1;
}

// ---------------------------------------------------------------- CSR build (keyed by dst, rows padded to 8)
__global__ __launch_bounds__(256) void k_count(const int* __restrict__ ei, int* deg) {
    int e = blockIdx.x * 256 + threadIdx.x;
    if (e >= NEDGES) return;
    atomicAdd(&deg[ei[NEDGES + e]], 1);
}

__global__ __launch_bounds__(256) void k_scan_chunk(const int* __restrict__ deg,
                                                    int* rowptr, int* part) {
    __shared__ int sums[256];
    int c = blockIdx.x, t = threadIdx.x;
    int base = c * SCAN_CHUNK;
    int v[8]; int s = 0;
#pragma unroll
    for (int i = 0; i < 8; i++) {
        int idx = base + t * 8 + i;
        v[i] = (idx < NNODES) ? ((deg[idx] + 7) & ~7) : 0;   // padded row size
        s += v[i];
    }
    sums[t] = s;
    __syncthreads();
    for (int off = 1; off < 256; off <<= 1) {
        int x = (t >= off) ? sums[t - off] : 0;
        __syncthreads();
        sums[t] += x;
        __syncthreads();
    }
    int run = (t == 0) ? 0 : sums[t - 1];
#pragma unroll
    for (int i = 0; i < 8; i++) {
        int idx = base + t * 8 + i;
        if (idx < NNODES) rowptr[idx] = run;
        run += v[i];
    }
    if (t == 255) part[c] = sums[255];
}

__global__ void k_scan_part(int* part, int nc) {
    if (threadIdx.x == 0) {
        int run = 0;
        for (int c = 0; c < nc; c++) { int v = part[c]; part[c] = run; run += v; }
    }
}

__global__ __launch_bounds__(256) void k_scan_add(int* rowptr, int* cursor,
                                                  const int* __restrict__ part) {
    int i = blockIdx.x * 256 + threadIdx.x;
    if (i >= NNODES) return;
    int v = rowptr[i] + part[i >> 11];
    rowptr[i] = v;
    cursor[i] = v;
}

__global__ __launch_bounds__(256) void k_fill(const int* __restrict__ ei,
                                              int* cursor, int* srcs, int* dsts) {
    int e = blockIdx.x * 256 + threadIdx.x;
    if (e >= EN) return;
    int src, dst;
    if (e < NEDGES) { src = ei[e]; dst = ei[NEDGES + e]; }
    else            { src = dst = e - NEDGES; }
    int pos = atomicAdd(&cursor[dst], 1);
    srcs[pos] = src;
    dsts[pos] = dst;
}

// ---------------------------------------------------------------- per-edge coefficients (padded dst-CSR order)
// evs[e] = exp(leakyrelu(as_[src]+ad_[dst])), 0 for padding slots (dst<0).
// Softmax without max subtraction (shift-invariant; logits O(1) here).
__global__ __launch_bounds__(256) void k_coef(const int* __restrict__ srcs,
                                              const int* __restrict__ dsts,
                                              const float* __restrict__ as_,
                                              const float* __restrict__ ad_,
                                              float* __restrict__ evs) {
    int e = blockIdx.x * 256 + threadIdx.x;
    if (e >= ALLOCE) return;
    int d = dsts[e];
    float ev = 0.f;
    if (d >= 0) {
        float al = as_[srcs[e]] + ad_[d];
        al = (al > 0.f) ? al : 0.2f * al;
        ev = __expf(al);
    }
    evs[e] = ev;
}

// ---------------------------------------------------------------- GEMM (C[M,128] = A[M,K] @ B[K,128]) -> bf16 C (paired words)
template <int K, bool ABF>
__global__ __launch_bounds__(256) void k_gemm(const void* __restrict__ Av,
                                              const float* __restrict__ B,
                                              u16* __restrict__ C, int M) {
    __shared__ float As[16][128];
    __shared__ float Bs[16][128];
    int bm = blockIdx.x * 128;
    int tid = threadIdx.x;
    int tx = tid & 15, ty = tid >> 4;
    float acc[8][8] = {};
    for (int k0 = 0; k0 < K; k0 += 16) {
#pragma unroll
        for (int q = tid; q < 512; q += 256) {       // A tile -> As[k][m] (transposed)
            int m = q >> 2, kq = (q & 3) << 2;
            int row = bm + m;
            if (ABF) {
                const u16* A = (const u16*)Av;
                uint2 v = make_uint2(0u, 0u);
                if (row < M) v = *(const uint2*)(A + (size_t)row * K + k0 + kq);
                As[kq + 0][m] = bfl(v.x); As[kq + 1][m] = bfh(v.x);
                As[kq + 2][m] = bfl(v.y); As[kq + 3][m] = bfh(v.y);
            } else {
                const float* A = (const float*)Av;
                float4 v = make_float4(0.f, 0.f, 0.f, 0.f);
                if (row < M) v = *(const float4*)(A + (size_t)row * K + k0 + kq);
                As[kq + 0][m] = v.x; As[kq + 1][m] = v.y;
                As[kq + 2][m] = v.z; As[kq + 3][m] = v.w;
            }
        }
#pragma unroll
        for (int q = tid; q < 512; q += 256) {       // B tile
            int kk = q >> 5, n4 = (q & 31) << 2;
            *(float4*)(&Bs[kk][n4]) = *(const float4*)(B + (size_t)(k0 + kk) * 128 + n4);
        }
        __syncthreads();
#pragma unroll
        for (int kk = 0; kk < 16; kk++) {
            float a[8], b[8];
            *(float4*)(a)     = *(float4*)(&As[kk][ty * 8]);
            *(float4*)(a + 4) = *(float4*)(&As[kk][ty * 8 + 4]);
            *(float4*)(b)     = *(float4*)(&Bs[kk][tx * 8]);
            *(float4*)(b + 4) = *(float4*)(&Bs[kk][tx * 8 + 4]);
#pragma unroll
            for (int i = 0; i < 8; i++)
#pragma unroll
                for (int j = 0; j < 8; j++)
                    acc[i][j] = fmaf(a[i], b[j], acc[i][j]);
        }
        __syncthreads();
    }
#pragma unroll
    for (int i = 0; i < 8; i++) {
        int row = bm + ty * 8 + i;
        if (row < M) {
            uint4 o;
            o.x = f2bf(acc[i][0]) | (f2bf(acc[i][1]) << 16);
            o.y = f2bf(acc[i][2]) | (f2bf(acc[i][3]) << 16);
            o.z = f2bf(acc[i][4]) | (f2bf(acc[i][5]) << 16);
            o.w = f2bf(acc[i][6]) | (f2bf(acc[i][7]) << 16);
            *(uint4*)(C + (size_t)row * 128 + tx * 8) = o;
        }
    }
}

// ---------------------------------------------------------------- attention dot products (wave per node, bf16 h)
__global__ __launch_bounds__(256) void k_dots(const u32* __restrict__ h,
                                              const float* __restrict__ asrc,
                                              const float* __restrict__ adst,
                                              float* as_, float* ad_) {
    int wid = (blockIdx.x * 256 + threadIdx.x) >> 6;
    int lane = threadIdx.x & 63;
    if (wid >= NNODES) return;
    u32 u = h[(size_t)wid * 64 + lane];
    float vx = bfl(u), vy = bfh(u);
    float2 as2 = ((const float2*)asrc)[lane];
    float2 ad2 = ((const float2*)adst)[lane];
    float s = vx * as2.x + vy * as2.y;
    float d = vx * ad2.x + vy * ad2.y;
#pragma unroll
    for (int off = 32; off; off >>= 1) {
        s += __shfl_xor(s, off);
        d += __shfl_xor(d, off);
    }
    if (lane == 0) { as_[wid] = s; ad_[wid] = d; }
}

// ---------------------------------------------------------------- GAT aggregation (wave per dst node)
// 4 random rows per dwordx4 instruction: lane l gathers uint4 (features
// 8i..8i+7, i=l&15) of edge q=l>>4's src row -> 1KB per vmem instruction
// (R2-R6 showed throughput scales with bytes/instr, not instr count).
// Rows padded to 8 slots (src=0, ev=0) -> no tail logic, aligned meta.
// Quarter-replicated accumulators merged by shfl_xor(16/32) at the end.
template <bool RELU, bool GATE, bool OUTBF>
__global__ __launch_bounds__(256) void k_agg(
    const u32* __restrict__ h, const int* __restrict__ srcs,
    const float* __restrict__ evs, const int* __restrict__ rowptr,
    const int* __restrict__ rowend,
    const float* __restrict__ bias, void* __restrict__ outv,
    const float* __restrict__ gateW, const float* __restrict__ gateB,
    float* __restrict__ gatev, float* __restrict__ gs,
    const int* __restrict__ batch) {
    int tid = threadIdx.x;
    int w = tid >> 6, lane = tid & 63;
    int wid = blockIdx.x * 4 + w;
    if (wid >= NNODES) return;
    int row = rowptr[wid];                       // multiple of 8
    int dg = rowend[wid] - row;                  // real degree
    int q = lane >> 4;                           // edge slot within group of 4
    int i = lane & 15;                           // feature slice: words 4i..4i+3

    float ssum = 0.f;
    float2 a0 = {0.f, 0.f}, a1 = {0.f, 0.f}, a2 = {0.f, 0.f}, a3 = {0.f, 0.f};

#pragma unroll 2
    for (int cb = 0; cb < dg; cb += 8) {
        int4   s03 = *(const int4*)(srcs + row + cb);
        int4   s47 = *(const int4*)(srcs + row + cb + 4);
        float4 e03 = *(const float4*)(evs + row + cb);
        float4 e47 = *(const float4*)(evs + row + cb + 4);
        // per-lane select of this quarter's edge (group A: edges cb..cb+3)
        int   tA0 = (q & 1) ? s03.y : s03.x;
        int   tA1 = (q & 1) ? s03.w : s03.z;
        int   sA  = (q & 2) ? tA1 : tA0;
        float fA0 = (q & 1) ? e03.y : e03.x;
        float fA1 = (q & 1) ? e03.w : e03.z;
        float eA  = (q & 2) ? fA1 : fA0;
        // group B: edges cb+4..cb+7
        int   tB0 = (q & 1) ? s47.y : s47.x;
        int   tB1 = (q & 1) ? s47.w : s47.z;
        int   sB  = (q & 2) ? tB1 : tB0;
        float fB0 = (q & 1) ? e47.y : e47.x;
        float fB1 = (q & 1) ? e47.w : e47.z;
        float eB  = (q & 2) ? fB1 : fB0;
        uint4 vA = *(const uint4*)(h + (size_t)sA * 64 + 4 * i);
        uint4 vB = *(const uint4*)(h + (size_t)sB * 64 + 4 * i);
        ssum += eA + eB;
        a0.x = fmaf(eA, bfl(vA.x), a0.x); a0.y = fmaf(eA, bfh(vA.x), a0.y);
        a1.x = fmaf(eA, bfl(vA.y), a1.x); a1.y = fmaf(eA, bfh(vA.y), a1.y);
        a2.x = fmaf(eA, bfl(vA.z), a2.x); a2.y = fmaf(eA, bfh(vA.z), a2.y);
        a3.x = fmaf(eA, bfl(vA.w), a3.x); a3.y = fmaf(eA, bfh(vA.w), a3.y);
        a0.x = fmaf(eB, bfl(vB.x), a0.x); a0.y = fmaf(eB, bfh(vB.x), a0.y);
        a1.x = fmaf(eB, bfl(vB.y), a1.x); a1.y = fmaf(eB, bfh(vB.y), a1.y);
        a2.x = fmaf(eB, bfl(vB.z), a2.x); a2.y = fmaf(eB, bfh(vB.z), a2.y);
        a3.x = fmaf(eB, bfl(vB.w), a3.x); a3.y = fmaf(eB, bfh(vB.w), a3.y);
    }
    // merge the 4 quarter-replicas (lanes differing in bits 4,5 share slice i)
    ssum += __shfl_xor(ssum, 16);  ssum += __shfl_xor(ssum, 32);
    a0.x += __shfl_xor(a0.x, 16);  a0.x += __shfl_xor(a0.x, 32);
    a0.y += __shfl_xor(a0.y, 16);  a0.y += __shfl_xor(a0.y, 32);
    a1.x += __shfl_xor(a1.x, 16);  a1.x += __shfl_xor(a1.x, 32);
    a1.y += __shfl_xor(a1.y, 16);  a1.y += __shfl_xor(a1.y, 32);
    a2.x += __shfl_xor(a2.x, 16);  a2.x += __shfl_xor(a2.x, 32);
    a2.y += __shfl_xor(a2.y, 16);  a2.y += __shfl_xor(a2.y, 32);
    a3.x += __shfl_xor(a3.x, 16);  a3.x += __shfl_xor(a3.x, 32);
    a3.y += __shfl_xor(a3.y, 16);  a3.y += __shfl_xor(a3.y, 32);

    float inv = 1.f / (ssum + 1e-16f);
    float4 bA = ((const float4*)bias)[2 * i];
    float4 bB = ((const float4*)bias)[2 * i + 1];
    float f0 = a0.x * inv + bA.x, f1 = a0.y * inv + bA.y;
    float f2 = a1.x * inv + bA.z, f3 = a1.y * inv + bA.w;
    float f4 = a2.x * inv + bB.x, f5 = a2.y * inv + bB.y;
    float f6 = a3.x * inv + bB.z, f7 = a3.y * inv + bB.w;
    if (RELU) {
        f0 = fmaxf(f0, 0.f); f1 = fmaxf(f1, 0.f); f2 = fmaxf(f2, 0.f);
        f3 = fmaxf(f3, 0.f); f4 = fmaxf(f4, 0.f); f5 = fmaxf(f5, 0.f);
        f6 = fmaxf(f6, 0.f); f7 = fmaxf(f7, 0.f);
    }
    if (lane < 16) {
        if (OUTBF) {
            uint4 o;
            o.x = f2bf(f0) | (f2bf(f1) << 16);
            o.y = f2bf(f2) | (f2bf(f3) << 16);
            o.z = f2bf(f4) | (f2bf(f5) << 16);
            o.w = f2bf(f6) | (f2bf(f7) << 16);
            ((uint4*)outv)[(size_t)wid * 16 + i] = o;
        } else {
            float* o = (float*)outv + (size_t)wid * 128 + 8 * i;
            ((float4*)o)[0] = make_float4(f0, f1, f2, f3);
            ((float4*)o)[1] = make_float4(f4, f5, f6, f7);
        }
    }
    if (GATE) {
        float4 gA = ((const float4*)gateW)[2 * i];
        float4 gB = ((const float4*)gateW)[2 * i + 1];
        float g = f0 * gA.x + f1 * gA.y + f2 * gA.z + f3 * gA.w
                + f4 * gB.x + f5 * gB.y + f6 * gB.z + f7 * gB.w;
#pragma unroll
        for (int off = 8; off; off >>= 1) g += __shfl_xor(g, off);
        if (lane == 0) {
            float ge = __expf(g + gateB[0]);   // no max subtraction (shift-invariant)
            gatev[wid] = ge;
            atomicAdd(&gs[batch[wid]], ge);
        }
    }
}

// ---------------------------------------------------------------- attention pooling (batch is sorted)
__global__ __launch_bounds__(128) void k_pool(const float* __restrict__ h,
                                              const float* __restrict__ gatev,
                                              const float* __restrict__ gs,
                                              const int* __restrict__ batch,
                                              float* pooled) {
    int t = threadIdx.x;  // feature
    int chunk = (NNODES + gridDim.x - 1) / gridDim.x;
    int s0 = blockIdx.x * chunk;
    int s1 = s0 + chunk; if (s1 > NNODES) s1 = NNODES;
    if (s0 >= s1) return;
    int curg = batch[s0];
    float invs = 1.f / (gs[curg] + 1e-16f);
    float acc = 0.f;
    for (int i = s0; i < s1; i++) {
        int g = batch[i];
        if (g != curg) {
            atomicAdd(&pooled[curg * 128 + t], acc);
            acc = 0.f; curg = g;
            invs = 1.f / (gs[g] + 1e-16f);
        }
        acc += h[(size_t)i * 128 + t] * (gatev[i] * invs);
    }
    atomicAdd(&pooled[curg * 128 + t], acc);
}

// ---------------------------------------------------------------- final: relu(pooled) @ lin_W + lin_b
__global__ __launch_bounds__(64) void k_final(const float* __restrict__ pooled,
                                              const float* __restrict__ linW,
                                              const float* __restrict__ linb,
                                              float* __restrict__ out) {
    __shared__ float rowv[128];
    int g = blockIdx.x, t = threadIdx.x;
    rowv[t]      = fmaxf(pooled[g * 128 + t], 0.f);
    rowv[t + 64] = fmaxf(pooled[g * 128 + 64 + t], 0.f);
    __syncthreads();
    float acc = linb[t];
#pragma unroll 8
    for (int k = 0; k < 128; k++) acc = fmaf(rowv[k], linW[k * 64 + t], acc);
    out[g * 64 + t] = acc;
}

// ---------------------------------------------------------------- launch
extern "C" void kernel_launch(void* const* d_in, const int* in_sizes, int n_in,
                              void* d_out, int out_size, void* d_ws, size_t ws_size,
                              hipStream_t stream) {
    const float* x     = (const float*)d_in[0];
    const int*   ei    = (const int*)d_in[1];
    const int*   batch = (const int*)d_in[2];
    const float* W1    = (const float*)d_in[3];
    const float* a1s   = (const float*)d_in[4];
    const float* a1d   = (const float*)d_in[5];
    const float* b1    = (const float*)d_in[6];
    const float* W2    = (const float*)d_in[7];
    const float* a2s   = (const float*)d_in[8];
    const float* a2d   = (const float*)d_in[9];
    const float* b2    = (const float*)d_in[10];
    const float* gateW = (const float*)d_in[11];
    const float* gateB = (const float*)d_in[12];
    const float* linW  = (const float*)d_in[13];
    const float* linb  = (const float*)d_in[14];
    float* out = (float*)d_out;

    char* p = (char*)d_ws;
    auto alloc = [&](size_t bytes) -> void* {
        void* r = (void*)p;
        p += (bytes + 255) & ~(size_t)255;
        return r;
    };
    u16*   hb     = (u16*)alloc((size_t)NNODES * 128 * 2);   // GEMM out (bf16 paired words)
    u16*   h1a    = (u16*)alloc((size_t)NNODES * 128 * 2);   // conv1 agg out (bf16)
    float* bufF   = (float*)alloc((size_t)NNODES * 128 * 4); // conv2 agg out (fp32)
    int*   srcs   = (int*)alloc((size_t)ALLOCE * 4);
    int*   dsts   = (int*)alloc((size_t)ALLOCE * 4);
    float* evs    = (float*)alloc((size_t)ALLOCE * 4);
    float* as_    = (float*)alloc((size_t)NNODES * 4);
    float* ad_    = (float*)alloc((size_t)NNODES * 4);
    float* gatev  = (float*)alloc((size_t)NNODES * 4);
    int*   deg    = (int*)alloc((size_t)NNODES * 4);
    int*   rowptr = (int*)alloc((size_t)NNODES * 4);
    int*   cursor = (int*)alloc((size_t)NNODES * 4);
    int*   part   = (int*)alloc(64 * 4);
    float* gs     = (float*)alloc(NG * 4);
    float* pooled = (float*)alloc((size_t)NG * HID * 4);

    const int gN   = (NNODES + 255) / 256;        // 391
    const int gE   = (NEDGES + 255) / 256;
    const int gEN  = (EN + 255) / 256;
    const int gAE  = (ALLOCE + 255) / 256;
    const int gW   = (NNODES + 3) / 4;            // wave-per-node, 4 waves/block

    // padded dst-CSR build (same graph for both convs)
    k_init<<<gN, 256, 0, stream>>>(deg, gs, pooled);
    k_count<<<gE, 256, 0, stream>>>(ei, deg);
    k_scan_chunk<<<NCHUNK, 256, 0, stream>>>(deg, rowptr, part);
    k_scan_part<<<1, 64, 0, stream>>>(part, NCHUNK);
    k_scan_add<<<gN, 256, 0, stream>>>(rowptr, cursor, part);
    k_meta_init<<<gAE, 256, 0, stream>>>(srcs, dsts);
    k_fill<<<gEN, 256, 0, stream>>>(ei, cursor, srcs, dsts);
    // after k_fill, cursor[n] == rowptr[n] + real degree

    // conv1
    k_gemm<256, false><<<(NNODES + 127) / 128, 256, 0, stream>>>(x, W1, hb, NNODES);
    k_dots<<<gW, 256, 0, stream>>>((const u32*)hb, a1s, a1d, as_, ad_);
    k_coef<<<gAE, 256, 0, stream>>>(srcs, dsts, as_, ad_, evs);
    k_agg<true, false, true><<<gW, 256, 0, stream>>>((const u32*)hb, srcs, evs,
                                                     rowptr, cursor, b1, h1a,
                                                     nullptr, nullptr, nullptr,
                                                     nullptr, nullptr);
    // conv2
    k_gemm<128, true><<<(NNODES + 127) / 128, 256, 0, stream>>>(h1a, W2, hb, NNODES);
    k_dots<<<gW, 256, 0, stream>>>((const u32*)hb, a2s, a2d, as_, ad_);
    k_coef<<<gAE, 256, 0, stream>>>(srcs, dsts, as_, ad_, evs);
    k_agg<false, true, false><<<gW, 256, 0, stream>>>((const u32*)hb, srcs, evs,
                                                      rowptr, cursor, b2, bufF,
                                                      gateW, gateB, gatev, gs, batch);
    // global attention pooling + final linear
    k_pool<<<512, 128, 0, stream>>>(bufF, gatev, gs, batch, pooled);
    k_final<<<NG, 64, 0, stream>>>(pooled, linW, linb, out);
}